// Round 3
// baseline (14.357 us; speedup 1.0000x reference)
//
#include <hip/hip_runtime.h>

#define NATOMS 10000
#define MAXNB  32
#define NRAD   16   // RAD_ORDER 15 -> T_0..T_15
#define NANG   8    // ANG_ORDER 7  -> T_0..T_7
#define WPB    4    // waves per 256-thread block; 2 atoms per wave -> 8 atoms/block
#define RSTRIDE 52  // 48 cols + pad, multiple of 4 -> 16B-aligned rows for b128 writes

// wave-local LDS fence: this wave's LDS writes are visible to its own lanes.
// Valid because every LDS buffer slice is read/written by exactly one wave
// (64 lanes in lockstep), so no cross-wave ordering is needed.
#define WAVE_LDS_FENCE() asm volatile("s_waitcnt lgkmcnt(0)" ::: "memory")

__global__ __launch_bounds__(256, 2) void cheby_desc_kernel(
    const int*   __restrict__ species,   // [N]
    const int*   __restrict__ nb_idx,    // [N, 32]
    const float* __restrict__ nb_vec,    // [N, 32, 3]
    float*       __restrict__ out)       // [N, 48]
{
    const int lane = threadIdx.x & 63;
    const int wv   = threadIdx.x >> 6;
    const int sub  = lane >> 5;          // which of the wave's 2 atoms
    const int nb   = lane & 31;          // neighbor index
    const int abase = blockIdx.x * (WPB * 2) + wv * 2;
    const int atom  = abase + sub;       // 10000 % 8 == 0 -> always in range

    __shared__ float4 nbd4[WPB][64];     // {ux, uy, uz, fca}
    __shared__ float  nbdS[WPB][64];     // fca * ts
    __shared__ float  red[WPB][64][RSTRIDE];

    // ---- per-neighbor (each neighbor handled by exactly one lane) ----
    const float vx = nb_vec[(atom * MAXNB + nb) * 3 + 0];
    const float vy = nb_vec[(atom * MAXNB + nb) * 3 + 1];
    const float vz = nb_vec[(atom * MAXNB + nb) * 3 + 2];
    const int   ni = nb_idx[atom * MAXNB + nb];
    const float ts = (float)(2 * species[ni] - 1);   // typespin(2) = {-1,+1}

    const float d     = __builtin_amdgcn_sqrtf(vx * vx + vy * vy + vz * vz);
    const float inv_d = __builtin_amdgcn_rcpf(fmaxf(d, 1e-8f));
    const float ux = vx * inv_d, uy = vy * inv_d, uz = vz * inv_d;

    const float PI = 3.14159265358979323846f;

    // ---- radial: rad[n] = g * T_n(xr) ----
    float xr = 2.0f * (d - 0.55f) * (1.0f / (6.0f - 0.55f)) - 1.0f;
    xr = fminf(fmaxf(xr, -1.0f), 1.0f);
    const float fcr = 0.5f * (__cosf(fminf(d, 6.0f) * (PI / 6.0f)) + 1.0f);
    const float g = ((d <= 6.0f) && (d > 0.55f)) ? fcr : 0.0f;

    float rad[NRAD];
    {
        rad[0] = g;
        rad[1] = g * xr;
        float Tp = 1.0f, Tc = xr;
        const float x2 = xr + xr;
        #pragma unroll
        for (int n = 2; n < NRAD; ++n) {
            const float Tn = x2 * Tc - Tp;
            rad[n] = g * Tn;
            Tp = Tc; Tc = Tn;
        }
    }

    // ---- angular per-neighbor quantities ----
    const float fca = ((d <= 4.0f) && (d > 0.55f))
                    ? 0.5f * (__cosf(fminf(d, 4.0f) * (PI / 4.0f)) + 1.0f) : 0.0f;
    const float fcats = fca * ts;        // w_ts = (fc ts)_j (fc ts)_k

    nbd4[wv][lane] = make_float4(ux, uy, uz, fca);
    nbdS[wv][lane] = fcats;
    WAVE_LDS_FENCE();

    // ---- pair loop: wave-uniform circulant offsets o = 1..16 ----
    // pairs (nb, (nb+o)&31): o in 1..15 covers each unordered pair once;
    // o=16 covers each diff-16 pair twice -> halve its weight.
    float aU[NANG], aW[NANG];
    #pragma unroll
    for (int n = 0; n < NANG; ++n) { aU[n] = 0.0f; aW[n] = 0.0f; }

    const int kb = sub * 32;
    #pragma unroll
    for (int o = 1; o <= 16; ++o) {
        const int k = kb + ((nb + o) & 31);
        const float4 K   = nbd4[wv][k];
        const float fkts = nbdS[wv][k];
        float c = ux * K.x + uy * K.y + uz * K.z;
        c = fminf(fmaxf(c, -1.0f), 1.0f);
        float w   = fca   * K.w;
        float wts = fcats * fkts;
        if (o == 16) { w *= 0.5f; wts *= 0.5f; }
        const float c2 = c + c;
        float Ta = 1.0f, Tb = c;
        aU[0] += w;     aW[0] += wts;
        aU[1] += w * c; aW[1] += wts * c;
        #pragma unroll
        for (int n = 2; n < NANG; ++n) {
            const float Tn = c2 * Tb - Ta;
            aU[n] += w * Tn;  aW[n] += wts * Tn;
            Ta = Tb; Tb = Tn;
        }
    }

    // ---- write 48 partials per lane, col layout == output layout ----
    // [0..15] rad_unw, [16..31] rad_w (= ts * rad), [32..39] aU, [40..47] aW
    {
        float* rr = &red[wv][lane][0];
        #pragma unroll
        for (int n = 0; n < NRAD; n += 4)
            *(float4*)(rr + n) = make_float4(rad[n], rad[n+1], rad[n+2], rad[n+3]);
        #pragma unroll
        for (int n = 0; n < NRAD; n += 4)
            *(float4*)(rr + 16 + n) = make_float4(ts*rad[n], ts*rad[n+1], ts*rad[n+2], ts*rad[n+3]);
        *(float4*)(rr + 32) = make_float4(aU[0], aU[1], aU[2], aU[3]);
        *(float4*)(rr + 36) = make_float4(aU[4], aU[5], aU[6], aU[7]);
        *(float4*)(rr + 40) = make_float4(aW[0], aW[1], aW[2], aW[3]);
        *(float4*)(rr + 44) = make_float4(aW[4], aW[5], aW[6], aW[7]);
    }
    WAVE_LDS_FENCE();

    // ---- column reduce: 96 tasks (2 atoms x 48 cols) over 64 lanes ----
    {
        const int s = (lane >= 48) ? 1 : 0;
        const int c = lane - 48 * s;
        const float* col = &red[wv][32 * s][c];
        float s0 = 0.f, s1 = 0.f, s2 = 0.f, s3 = 0.f;
        #pragma unroll
        for (int i = 0; i < 32; i += 4) {
            s0 += col[(i + 0) * RSTRIDE];
            s1 += col[(i + 1) * RSTRIDE];
            s2 += col[(i + 2) * RSTRIDE];
            s3 += col[(i + 3) * RSTRIDE];
        }
        out[(abase + s) * 48 + c] = (s0 + s1) + (s2 + s3);
    }
    if (lane < 32) {                      // tasks 64..95: atom1, cols 16..47
        const int c = 16 + lane;
        const float* col = &red[wv][32][c];
        float s0 = 0.f, s1 = 0.f, s2 = 0.f, s3 = 0.f;
        #pragma unroll
        for (int i = 0; i < 32; i += 4) {
            s0 += col[(i + 0) * RSTRIDE];
            s1 += col[(i + 1) * RSTRIDE];
            s2 += col[(i + 2) * RSTRIDE];
            s3 += col[(i + 3) * RSTRIDE];
        }
        out[(abase + 1) * 48 + c] = (s0 + s1) + (s2 + s3);
    }
}

extern "C" void kernel_launch(void* const* d_in, const int* in_sizes, int n_in,
                              void* d_out, int out_size, void* d_ws, size_t ws_size,
                              hipStream_t stream) {
    // setup_inputs order: positions(f32, UNUSED), species_indices(i32),
    //                     neighbor_indices(i32), neighbor_vectors(f32)
    const int*   species = (const int*)  d_in[1];
    const int*   nbidx   = (const int*)  d_in[2];
    const float* nbvec   = (const float*)d_in[3];
    float*       out     = (float*)      d_out;

    const int blocks = NATOMS / (WPB * 2);   // 1250
    cheby_desc_kernel<<<blocks, 256, 0, stream>>>(species, nbidx, nbvec, out);
}

// Round 4
// 11.087 us; speedup vs baseline: 1.2949x; 1.2949x over previous
//
#include <hip/hip_runtime.h>

#define NATOMS 10000
#define MAXNB  32
#define NRAD   16   // RAD_ORDER 15 -> T_0..T_15
#define NANG   8    // ANG_ORDER 7  -> T_0..T_7
#define WPB    4    // waves per 256-thread block; 2 atoms/wave -> 8 atoms/block
#define RSTR   36   // row stride (words): mult of 4 -> 16B-aligned rows, +4 pad vs 32 -> bank spread

// wave-local LDS fence: all of this wave's outstanding LDS ops complete.
// Valid sync because every LDS slice is touched by exactly one wave (lockstep).
#define WAVE_LDS_FENCE() asm volatile("s_waitcnt lgkmcnt(0)" ::: "memory")

__global__ __launch_bounds__(256, 6) void cheby_desc_kernel(
    const int*   __restrict__ species,   // [N]
    const int*   __restrict__ nb_idx,    // [N, 32]
    const float* __restrict__ nb_vec,    // [N, 32, 3]
    float*       __restrict__ out)       // [N, 48]
{
    const int lane = threadIdx.x & 63;
    const int wv   = threadIdx.x >> 6;
    const int sub  = lane >> 5;          // which of the wave's 2 atoms
    const int nb   = lane & 31;          // neighbor index
    const int abase = blockIdx.x * (WPB * 2) + wv * 2;
    const int atom  = abase + sub;       // 10000 % 8 == 0 -> in range

    __shared__ float4 nbd4[WPB][64];         // {ux, uy, uz, fca*ts}; fca = |w|
    __shared__ float  tsb[WPB][64];          // ts per neighbor
    __shared__ float  red[WPB][32][RSTR];    // transposed partials: [row][nb]

    // ---- per-neighbor ----
    const float* vp = nb_vec + (size_t)(atom * MAXNB + nb) * 3;
    const float vx = vp[0], vy = vp[1], vz = vp[2];
    const int   ni = nb_idx[atom * MAXNB + nb];
    const float ts = (float)(2 * species[ni] - 1);   // typespin(2) = {-1,+1}

    const float d     = __builtin_amdgcn_sqrtf(vx * vx + vy * vy + vz * vz);
    const float inv_d = __builtin_amdgcn_rcpf(fmaxf(d, 1e-8f));
    const float ux = vx * inv_d, uy = vy * inv_d, uz = vz * inv_d;
    const float PI = 3.14159265358979323846f;

    const float fca = ((d <= 4.0f) && (d > 0.55f))
                    ? 0.5f * (__cosf(fminf(d, 4.0f) * (PI / 4.0f)) + 1.0f) : 0.0f;
    const float fcats = fca * ts;            // fca recovered as |fcats|

    nbd4[wv][lane] = make_float4(ux, uy, uz, fcats);
    tsb[wv][lane]  = ts;

    // ---- radial partials, written transposed: row = sub*16 + c, word = nb ----
    {
        float xr = 2.0f * (d - 0.55f) * (1.0f / 5.45f) - 1.0f;
        xr = fminf(fmaxf(xr, -1.0f), 1.0f);
        const float fcr = 0.5f * (__cosf(fminf(d, 6.0f) * (PI / 6.0f)) + 1.0f);
        const float g = ((d <= 6.0f) && (d > 0.55f)) ? fcr : 0.0f;
        float* rb = &red[wv][sub * 16][nb];   // + c*RSTR, immediate offsets
        rb[0]    = g;
        rb[RSTR] = g * xr;
        float Tp = 1.0f, Tc = xr;
        const float x2 = xr + xr;
        #pragma unroll
        for (int n = 2; n < NRAD; ++n) {
            const float Tn = x2 * Tc - Tp;
            rb[n * RSTR] = g * Tn;
            Tp = Tc; Tc = Tn;
        }
    }
    WAVE_LDS_FENCE();

    // ---- radial reduce: 32 tasks (2 atoms x 16 cols), 2 lanes per task ----
    // lane = 2j+h: task j = row j (s = j>>4, c = j&15); halves combined via xor-1.
    {
        const int j = lane >> 1, h = lane & 1;
        const int s = j >> 4,  c = j & 15;
        const float* rr = &red[wv][j][h * 16];
        const float* tr = &tsb[wv][s * 32 + h * 16];   // broadcast across task lanes
        float sU = 0.0f, sW = 0.0f;
        #pragma unroll
        for (int i = 0; i < 4; ++i) {
            const float4 r4 = *(const float4*)(rr + 4 * i);
            const float4 t4 = *(const float4*)(tr + 4 * i);
            sU += (r4.x + r4.y) + (r4.z + r4.w);
            sW += t4.x * r4.x + t4.y * r4.y + t4.z * r4.z + t4.w * r4.w;
        }
        sU += __shfl_xor(sU, 1, 64);
        sW += __shfl_xor(sW, 1, 64);
        if (h == 0) {
            out[(abase + s) * 48 + c]      = sU;   // rad unweighted
            out[(abase + s) * 48 + 16 + c] = sW;   // rad typespin-weighted
        }
    }

    // ---- pair loop: circulant offsets o=1..16 over each atom's 32 neighbors ----
    float aU[NANG], aW[NANG];
    #pragma unroll
    for (int n = 0; n < NANG; ++n) { aU[n] = 0.0f; aW[n] = 0.0f; }

    const int kb = sub * 32;
    #pragma unroll
    for (int o = 1; o <= 16; ++o) {
        const int k = kb + ((nb + o) & 31);
        const float4 K = nbd4[wv][k];
        float c = ux * K.x + uy * K.y + uz * K.z;
        c = fminf(fmaxf(c, -1.0f), 1.0f);
        float wts = fcats * K.w;             // (fc ts)_j (fc ts)_k
        float w   = fabsf(wts);              // fc_j fc_k  (ts = +-1)
        if (o == 16) { w *= 0.5f; wts *= 0.5f; }   // diff-16 pairs visited twice
        const float c2 = c + c;
        float Ta = 1.0f, Tb = c;
        aU[0] += w;     aW[0] += wts;
        aU[1] += w * c; aW[1] += wts * c;
        #pragma unroll
        for (int n = 2; n < NANG; ++n) {
            const float Tn = c2 * Tb - Ta;
            aU[n] += w * Tn;  aW[n] += wts * Tn;
            Ta = Tb; Tb = Tn;
        }
    }

    // ---- angular partials: reuse the same 32 rows (rad reduce already consumed) ----
    WAVE_LDS_FENCE();
    {
        float* ab = &red[wv][sub * 16][nb];
        #pragma unroll
        for (int n = 0; n < NANG; ++n) {
            ab[n * RSTR]       = aU[n];      // rows sub*16 + 0..7
            ab[(8 + n) * RSTR] = aW[n];      // rows sub*16 + 8..15
        }
    }
    WAVE_LDS_FENCE();

    // ---- angular reduce: 32 tasks (2 atoms x 16 cols), 2 lanes per task ----
    {
        const int j = lane >> 1, h = lane & 1;
        const int s = j >> 4,  jj = j & 15;  // jj<8: aU[jj], else aW[jj-8]
        const float* rr = &red[wv][j][h * 16];
        float sv = 0.0f;
        #pragma unroll
        for (int i = 0; i < 4; ++i) {
            const float4 r4 = *(const float4*)(rr + 4 * i);
            sv += (r4.x + r4.y) + (r4.z + r4.w);
        }
        sv += __shfl_xor(sv, 1, 64);
        if (h == 0) out[(abase + s) * 48 + 32 + jj] = sv;
    }
}

extern "C" void kernel_launch(void* const* d_in, const int* in_sizes, int n_in,
                              void* d_out, int out_size, void* d_ws, size_t ws_size,
                              hipStream_t stream) {
    // setup_inputs order: positions(f32, UNUSED), species_indices(i32),
    //                     neighbor_indices(i32), neighbor_vectors(f32)
    const int*   species = (const int*)  d_in[1];
    const int*   nbidx   = (const int*)  d_in[2];
    const float* nbvec   = (const float*)d_in[3];
    float*       out     = (float*)      d_out;

    const int blocks = NATOMS / (WPB * 2);   // 1250
    cheby_desc_kernel<<<blocks, 256, 0, stream>>>(species, nbidx, nbvec, out);
}